// Round 5
// baseline (304.331 us; speedup 1.0000x reference)
//
#include <hip/hip_runtime.h>
#include <hip/hip_bf16.h>

// Problem constants
#define DIM   1024
#define NH    16
#define HD    64
#define BB    2
#define TT    2048
#define BT    (BB*TT)   // 4096 rows
#define BHN   (BB*NH)   // 32 (b,h) pairs

typedef __attribute__((ext_vector_type(8))) __bf16 bf16x8;
typedef __attribute__((ext_vector_type(4))) float  f32x4;

__device__ __forceinline__ unsigned short f2bf(float f) {
    unsigned int u = __float_as_uint(f);
    u = (u + 0x7fffu + ((u >> 16) & 1u)) >> 16;   // RNE
    return (unsigned short)u;
}

// async global->LDS, 16B per lane. LDS dest must be wave-uniform base (+lane*16 implicit).
__device__ __forceinline__ void gload_lds16(const unsigned short* g, unsigned short* l) {
    __builtin_amdgcn_global_load_lds(
        (const __attribute__((address_space(1))) unsigned int*)g,
        (__attribute__((address_space(3))) unsigned int*)l, 16, 0, 0);
}

// ---------------------------------------------------------------- cvt fp32->bf16
__global__ __launch_bounds__(256) void cvt_bf16(const float* __restrict__ in,
                                                unsigned short* __restrict__ out, int n) {
    int i = blockIdx.x * 256 + threadIdx.x;
    int base = i * 8;
    if (base >= n) return;
    float4 a = *reinterpret_cast<const float4*>(in + base);
    float4 b = *reinterpret_cast<const float4*>(in + base + 4);
    uint4 o;
    o.x = (unsigned)f2bf(a.x) | ((unsigned)f2bf(a.y) << 16);
    o.y = (unsigned)f2bf(a.z) | ((unsigned)f2bf(a.w) << 16);
    o.z = (unsigned)f2bf(b.x) | ((unsigned)f2bf(b.y) << 16);
    o.w = (unsigned)f2bf(b.z) | ((unsigned)f2bf(b.w) << 16);
    *reinterpret_cast<uint4*>(out + base) = o;
}

// ---------------------------------------------------------------- RoPE tables
__global__ __launch_bounds__(256) void build_rope(float* __restrict__ cosT,
                                                  float* __restrict__ sinT) {
    int i = blockIdx.x * 256 + threadIdx.x;
    if (i >= TT * 32) return;
    int t = i >> 5, j = i & 31;
    float freq = exp2f(-5.0f * (float)j * (1.0f / 32.0f));  // 32^(-j/32)
    float ang  = (float)t * freq;
    cosT[i] = cosf(ang);
    sinT[i] = sinf(ang);
}

// ---------------------------------------------------------------- GEMM: C[M][N] = A[M][K] * Bt[N][K]^T
// bf16 in, fp32 out. 128x128 tile, BK=64, 4 waves (2x2).
// Staging: global_load_lds width=16, linear LDS dest + pre-swizzled global source;
// reads use the same XOR-granule involution -> conflict-free ds_read_b128.
__global__ __launch_bounds__(256) void gemm_bt(const unsigned short* __restrict__ A,
                                               const unsigned short* __restrict__ Bt,
                                               float* __restrict__ C,
                                               int M, int N, int K) {
    __shared__ alignas(16) unsigned short sA[128 * 64];
    __shared__ alignas(16) unsigned short sB[128 * 64];
    const int t    = threadIdx.x;
    const int nb   = N >> 7;
    const int m0   = (blockIdx.x / nb) << 7;
    const int n0   = (blockIdx.x % nb) << 7;
    const int w    = t >> 6, lane = t & 63;
    const int wr   = w >> 1, wc = w & 1;
    const int lrow = lane & 15, lk = lane >> 4;
    const int r_   = t >> 3;            // staging row-within-32-group
    const int c_   = t & 7;             // linear 16B granule (LDS dest)
    const int pg   = c_ ^ (r_ & 7);     // swizzled granule (global source)

    f32x4 acc[4][4] = {};

    for (int kt = 0; kt < K; kt += 64) {
        __syncthreads();
#pragma unroll
        for (int i = 0; i < 4; i++) {
            gload_lds16(A  + (size_t)(m0 + i * 32 + r_) * K + kt + pg * 8, sA + i * 2048 + w * 512);
            gload_lds16(Bt + (size_t)(n0 + i * 32 + r_) * K + kt + pg * 8, sB + i * 2048 + w * 512);
        }
        __syncthreads();
#pragma unroll
        for (int ks = 0; ks < 2; ks++) {
            bf16x8 af[4], bfr[4];
#pragma unroll
            for (int mi = 0; mi < 4; mi++) {
                int rowa = wr * 64 + mi * 16 + lrow;
                int ga   = (ks * 4 + lk) ^ (rowa & 7);
                af[mi]   = *reinterpret_cast<const bf16x8*>(&sA[rowa * 64 + ga * 8]);
                int rowb = wc * 64 + mi * 16 + lrow;
                int gb   = (ks * 4 + lk) ^ (rowb & 7);
                bfr[mi]  = *reinterpret_cast<const bf16x8*>(&sB[rowb * 64 + gb * 8]);
            }
#pragma unroll
            for (int mi = 0; mi < 4; mi++)
#pragma unroll
                for (int ni = 0; ni < 4; ni++)
                    acc[mi][ni] = __builtin_amdgcn_mfma_f32_16x16x32_bf16(af[mi], bfr[ni], acc[mi][ni], 0, 0, 0);
        }
    }
    // epilogue: C/D layout col=lane&15, row=(lane>>4)*4+i
#pragma unroll
    for (int mi = 0; mi < 4; mi++)
#pragma unroll
        for (int ni = 0; ni < 4; ni++) {
            int row = m0 + wr * 64 + mi * 16 + lk * 4;
            int col = n0 + wc * 64 + ni * 16 + lrow;
#pragma unroll
            for (int i = 0; i < 4; i++)
                C[(size_t)(row + i) * N + col] = acc[mi][ni][i];
        }
}

// ---------------------------------------------------------------- RMSNorm + RoPE epilogue
// One wave per (sel,b,t,h) row of 64. sel: 0=q,1=k,2=v(copy).
// Q gets *0.125*log2(e) folded in (exp2-based softmax downstream).
__global__ __launch_bounds__(256) void norm_rope(const float* __restrict__ qkv,
                                                 const float* __restrict__ cosT,
                                                 const float* __restrict__ sinT,
                                                 const float* __restrict__ qw,
                                                 const float* __restrict__ kw,
                                                 unsigned short* __restrict__ Qo,
                                                 unsigned short* __restrict__ Ko,
                                                 unsigned short* __restrict__ Vo) {
    int wv = threadIdx.x >> 6, lane = threadIdx.x & 63;
    int rid = blockIdx.x * 4 + wv;           // 0 .. 3*65536-1
    int sel = rid >> 16;
    int rem = rid & 65535;
    int h   = rem & 15;
    int bt  = rem >> 4;                      // b*T + t
    int tp  = bt & (TT - 1);
    int b   = bt >> 11;
    float v = qkv[(size_t)bt * 3072 + sel * 1024 + h * 64 + lane];
    unsigned short* dst = (sel == 0) ? Qo : ((sel == 1) ? Ko : Vo);
    size_t didx = ((size_t)(b * NH + h) * TT + tp) * 64 + lane;
    float outv;
    if (sel < 2) {
        float ss = v * v;
#pragma unroll
        for (int m = 32; m; m >>= 1) ss += __shfl_xor(ss, m);
        float r = rsqrtf(ss * (1.0f / 64.0f) + 1e-6f);
        const float* wgt = sel ? kw : qw;
        float nv = v * r * wgt[lane];
        float other = __shfl_xor(nv, 32);
        int j = lane & 31;
        float c = cosT[tp * 32 + j], s = sinT[tp * 32 + j];
        outv = (lane < 32) ? (nv * c - other * s) : (nv * c + other * s);
        if (sel == 0) outv *= 0.125f * 1.4426950408889634f;  // scale * log2(e): exp2 softmax
    } else {
        outv = v;
    }
    dst[didx] = f2bf(outv);
}

// ---------------------------------------------------------------- V transpose: [bh][t][d] -> [bh][d][t]
__global__ __launch_bounds__(256) void transpose_v(const unsigned short* __restrict__ Vb,
                                                   unsigned short* __restrict__ Vt) {
    __shared__ unsigned short s[64 * 68];
    const int t0 = blockIdx.x * 64, bh = blockIdx.y;
    const unsigned short* src = Vb + (size_t)bh * TT * 64;
    const int r = threadIdx.x >> 2, g4 = threadIdx.x & 3;
#pragma unroll
    for (int p = 0; p < 2; p++) {
        int g = g4 + p * 4;
        *reinterpret_cast<uint4*>(&s[r * 68 + g * 8]) =
            *reinterpret_cast<const uint4*>(src + (size_t)(t0 + r) * 64 + g * 8);
    }
    __syncthreads();
#pragma unroll
    for (int p = 0; p < 2; p++) {
        int tt = (g4 + p * 4) * 8;
        unsigned short tmp[8];
#pragma unroll
        for (int j = 0; j < 8; j++) tmp[j] = s[(tt + j) * 68 + r];   // column r = d
        *reinterpret_cast<uint4*>(Vt + ((size_t)bh * 64 + r) * TT + t0 + tt) =
            *reinterpret_cast<uint4*>(tmp);
    }
}

// ---------------------------------------------------------------- causal flash attention
// Block: (x, bh) with qt = (x + bh) & 31. 4 waves, QBLK=64, KVBLK=64.
// exp2-based online softmax with defer-max (THR=8) and deferred l-reduce.
// K/V register-prefetch (T14): next tile's loads issue before current compute.
__global__ __launch_bounds__(256) void attn_fwd(const unsigned short* __restrict__ Qm,
                                                const unsigned short* __restrict__ Km,
                                                const unsigned short* __restrict__ Vt,
                                                unsigned short* __restrict__ Om) {
    __shared__ alignas(16) unsigned short sQ[64 * 68];
    __shared__ alignas(16) unsigned short sK[64 * 68];
    __shared__ alignas(16) unsigned short sVT[64 * 68];   // [d][kv]
    __shared__ alignas(16) unsigned short sP[4][16 * 68]; // per-wave P tile
    const int bh = blockIdx.y;
    const int qt = (blockIdx.x + blockIdx.y) & 31;   // balance triangular work across CUs
    const int b = bh >> 4, h = bh & 15;
    const unsigned short* Qp = Qm + (size_t)bh * TT * 64;
    const unsigned short* Kp = Km + (size_t)bh * TT * 64;
    const unsigned short* Vp = Vt + (size_t)bh * 64 * TT;   // [d][t]
    const int t = threadIdx.x, wv = t >> 6, lane = t & 63;
    const int lrow = lane & 15, lk = lane >> 4;
    const int r_ = t >> 3, c_ = t & 7;
    const int d_ = t >> 2, g_ = t & 3;

    // stage Q tile once
#pragma unroll
    for (int i = 0; i < 2; i++) {
        int r = i * 32 + r_;
        *reinterpret_cast<uint4*>(&sQ[r * 68 + c_ * 8]) =
            *reinterpret_cast<const uint4*>(Qp + (size_t)(qt * 64 + r) * 64 + c_ * 8);
    }
    // K/V prefetch registers (tile 0)
    uint4 kreg[2], vreg[2];
#pragma unroll
    for (int i = 0; i < 2; i++)
        kreg[i] = *reinterpret_cast<const uint4*>(Kp + (size_t)(i * 32 + r_) * 64 + c_ * 8);
#pragma unroll
    for (int p = 0; p < 2; p++)
        vreg[p] = *reinterpret_cast<const uint4*>(Vp + (size_t)d_ * TT + (g_ + p * 4) * 8);
#pragma unroll
    for (int i = 0; i < 2; i++)
        *reinterpret_cast<uint4*>(&sK[(i * 32 + r_) * 68 + c_ * 8]) = kreg[i];
#pragma unroll
    for (int p = 0; p < 2; p++)
        *reinterpret_cast<uint4*>(&sVT[d_ * 68 + (g_ + p * 4) * 8]) = vreg[p];
    __syncthreads();

    bf16x8 aq0 = *reinterpret_cast<const bf16x8*>(&sQ[(wv * 16 + lrow) * 68 + lk * 8]);
    bf16x8 aq1 = *reinterpret_cast<const bf16x8*>(&sQ[(wv * 16 + lrow) * 68 + 32 + lk * 8]);

    f32x4 o[4] = {};
    float mrun[4], lsum[4];
#pragma unroll
    for (int i = 0; i < 4; i++) { mrun[i] = -__builtin_inff(); lsum[i] = 0.0f; }

    for (int kt = 0; kt <= qt; kt++) {
        const bool more = (kt < qt);
        // issue next tile's K/V loads early: latency hides under compute below
        if (more) {
#pragma unroll
            for (int i = 0; i < 2; i++)
                kreg[i] = *reinterpret_cast<const uint4*>(Kp + (size_t)((kt + 1) * 64 + i * 32 + r_) * 64 + c_ * 8);
#pragma unroll
            for (int p = 0; p < 2; p++)
                vreg[p] = *reinterpret_cast<const uint4*>(Vp + (size_t)d_ * TT + (kt + 1) * 64 + (g_ + p * 4) * 8);
        }

        // S = Q K^T  (scale*log2e pre-folded into Q)
        f32x4 s[4];
#pragma unroll
        for (int nt = 0; nt < 4; nt++) {
            f32x4 z = {0.f, 0.f, 0.f, 0.f};
            z = __builtin_amdgcn_mfma_f32_16x16x32_bf16(
                aq0, *reinterpret_cast<const bf16x8*>(&sK[(nt * 16 + lrow) * 68 + lk * 8]), z, 0, 0, 0);
            z = __builtin_amdgcn_mfma_f32_16x16x32_bf16(
                aq1, *reinterpret_cast<const bf16x8*>(&sK[(nt * 16 + lrow) * 68 + 32 + lk * 8]), z, 0, 0, 0);
            s[nt] = z;
        }
        if (kt == qt) {   // diagonal tile: causal mask (kv_local > q_local)
#pragma unroll
            for (int nt = 0; nt < 4; nt++)
#pragma unroll
                for (int i = 0; i < 4; i++)
                    if (nt * 16 + lrow > wv * 16 + lk * 4 + i) s[nt][i] = -__builtin_inff();
        }

        // defer-max online softmax (log2 domain)
        float pm[4];
#pragma unroll
        for (int i = 0; i < 4; i++)
            pm[i] = fmaxf(fmaxf(s[0][i], s[1][i]), fmaxf(s[2][i], s[3][i]));
        bool skip = __all(pm[0] <= mrun[0] + 8.0f && pm[1] <= mrun[1] + 8.0f &&
                          pm[2] <= mrun[2] + 8.0f && pm[3] <= mrun[3] + 8.0f);
        if (!skip) {
#pragma unroll
            for (int i = 0; i < 4; i++) {
                float a = pm[i];
#pragma unroll
                for (int msk = 8; msk; msk >>= 1) a = fmaxf(a, __shfl_xor(a, msk));
                float mn = fmaxf(mrun[i], a);
                float fsc = exp2f(mrun[i] - mn);
                mrun[i] = mn;
                lsum[i] *= fsc;
#pragma unroll
                for (int dt = 0; dt < 4; dt++) o[dt][i] *= fsc;
            }
        }
#pragma unroll
        for (int nt = 0; nt < 4; nt++)
#pragma unroll
            for (int i = 0; i < 4; i++) {
                float p = exp2f(s[nt][i] - mrun[i]);
                s[nt][i] = p;
            }
#pragma unroll
        for (int i = 0; i < 4; i++)
            lsum[i] += (s[0][i] + s[1][i]) + (s[2][i] + s[3][i]);   // per-lane partial; reduced at end

        // P -> LDS (wave-private, pad 68 => conflict-free u16 writes) -> A-frags
        unsigned short* myP = &sP[wv][0];
#pragma unroll
        for (int nt = 0; nt < 4; nt++)
#pragma unroll
            for (int i = 0; i < 4; i++)
                myP[(lk * 4 + i) * 68 + nt * 16 + lrow] = f2bf(s[nt][i]);
        bf16x8 pa0 = *reinterpret_cast<const bf16x8*>(&myP[lrow * 68 + lk * 8]);
        bf16x8 pa1 = *reinterpret_cast<const bf16x8*>(&myP[lrow * 68 + 32 + lk * 8]);
#pragma unroll
        for (int dt = 0; dt < 4; dt++) {
            o[dt] = __builtin_amdgcn_mfma_f32_16x16x32_bf16(
                pa0, *reinterpret_cast<const bf16x8*>(&sVT[(dt * 16 + lrow) * 68 + lk * 8]), o[dt], 0, 0, 0);
            o[dt] = __builtin_amdgcn_mfma_f32_16x16x32_bf16(
                pa1, *reinterpret_cast<const bf16x8*>(&sVT[(dt * 16 + lrow) * 68 + 32 + lk * 8]), o[dt], 0, 0, 0);
        }

        __syncthreads();            // all waves done reading sK/sVT
        if (more) {                 // commit prefetched tile kt+1
#pragma unroll
            for (int i = 0; i < 2; i++)
                *reinterpret_cast<uint4*>(&sK[(i * 32 + r_) * 68 + c_ * 8]) = kreg[i];
#pragma unroll
            for (int p = 0; p < 2; p++)
                *reinterpret_cast<uint4*>(&sVT[d_ * 68 + (g_ + p * 4) * 8]) = vreg[p];
            __syncthreads();
        }
    }

    // final cross-lane l reduce (deferred), then normalize + store to [B*T][1024]
    float inv[4];
#pragma unroll
    for (int i = 0; i < 4; i++) {
        float a = lsum[i];
#pragma unroll
        for (int msk = 8; msk; msk >>= 1) a += __shfl_xor(a, msk);
        inv[i] = 1.0f / a;
    }
    int qrow = qt * 64 + wv * 16 + lk * 4;
#pragma unroll
    for (int dt = 0; dt < 4; dt++)
#pragma unroll
        for (int i = 0; i < 4; i++) {
            size_t idx = ((size_t)(b * TT + qrow + i)) * 1024 + h * 64 + dt * 16 + lrow;
            Om[idx] = f2bf(o[dt][i] * inv[i]);
        }
}

// ---------------------------------------------------------------- launch
extern "C" void kernel_launch(void* const* d_in, const int* in_sizes, int n_in,
                              void* d_out, int out_size, void* d_ws, size_t ws_size,
                              hipStream_t stream) {
    const float* x      = (const float*)d_in[0];
    const float* w_qkv  = (const float*)d_in[1];
    const float* w_proj = (const float*)d_in[2];
    const float* qw     = (const float*)d_in[3];
    const float* kw     = (const float*)d_in[4];
    float* out = (float*)d_out;
    char* ws = (char*)d_ws;

    // workspace layout (bytes); total ~92.8 MB (Vt aliases dead qkvf region)
    unsigned short* xb     = (unsigned short*)(ws + 0);            // 8,388,608  (aliased by attnb later)
    unsigned short* wqkvb  = (unsigned short*)(ws + 8388608);      // 6,291,456
    unsigned short* wprojb = (unsigned short*)(ws + 14680064);     // 2,097,152
    float*          qkvf   = (float*)(ws + 16777216);              // 50,331,648 (dead after norm_rope)
    unsigned short* Vtb    = (unsigned short*)(ws + 16777216);     // 8,388,608  (alias into qkvf)
    unsigned short* Qb     = (unsigned short*)(ws + 67108864);     // 8,388,608
    unsigned short* Kb     = (unsigned short*)(ws + 75497472);     // 8,388,608
    unsigned short* Vb     = (unsigned short*)(ws + 83886080);     // 8,388,608
    float*          cosT   = (float*)(ws + 92274688);              // 262,144
    float*          sinT   = (float*)(ws + 92536832);              // 262,144
    unsigned short* attnb  = xb;  // alias: x consumed by GEMM1 before attn writes

    cvt_bf16<<<2048, 256, 0, stream>>>(x, xb, BT * DIM);
    cvt_bf16<<<1536, 256, 0, stream>>>(w_qkv, wqkvb, 3 * DIM * DIM);
    cvt_bf16<<<512, 256, 0, stream>>>(w_proj, wprojb, DIM * DIM);
    build_rope<<<256, 256, 0, stream>>>(cosT, sinT);
    gemm_bt<<<(BT / 128) * (3 * DIM / 128), 256, 0, stream>>>(xb, wqkvb, qkvf, BT, 3 * DIM, DIM);
    norm_rope<<<3 * BT * NH / 4, 256, 0, stream>>>(qkvf, cosT, sinT, qw, kw, Qb, Kb, Vb);
    transpose_v<<<dim3(TT / 64, BHN), 256, 0, stream>>>(Vb, Vtb);
    attn_fwd<<<dim3(TT / 64, BHN), 256, 0, stream>>>(Qb, Kb, Vtb, attnb);
    gemm_bt<<<(BT / 128) * (DIM / 128), 256, 0, stream>>>(attnb, wprojb, out, BT, DIM, DIM);
    (void)in_sizes; (void)n_in; (void)out_size; (void)ws_size;
}

// Round 13
// 256.143 us; speedup vs baseline: 1.1881x; 1.1881x over previous
//
#include <hip/hip_runtime.h>
#include <hip/hip_bf16.h>

// Problem constants
#define DIM   1024
#define NH    16
#define HD    64
#define BB    2
#define TT    2048
#define BT    (BB*TT)   // 4096 rows
#define BHN   (BB*NH)   // 32 (b,h) pairs

typedef __attribute__((ext_vector_type(8))) __bf16 bf16x8;
typedef __attribute__((ext_vector_type(4))) float  f32x4;

__device__ __forceinline__ unsigned short f2bf(float f) {
    unsigned int u = __float_as_uint(f);
    u = (u + 0x7fffu + ((u >> 16) & 1u)) >> 16;   // RNE
    return (unsigned short)u;
}

// async global->LDS, 16B per lane. LDS dest must be wave-uniform base (+lane*16 implicit).
__device__ __forceinline__ void gload_lds16(const unsigned short* g, unsigned short* l) {
    __builtin_amdgcn_global_load_lds(
        (const __attribute__((address_space(1))) unsigned int*)g,
        (__attribute__((address_space(3))) unsigned int*)l, 16, 0, 0);
}

// ---------------------------------------------------------------- cvt fp32->bf16
__global__ __launch_bounds__(256) void cvt_bf16(const float* __restrict__ in,
                                                unsigned short* __restrict__ out, int n) {
    int i = blockIdx.x * 256 + threadIdx.x;
    int base = i * 8;
    if (base >= n) return;
    float4 a = *reinterpret_cast<const float4*>(in + base);
    float4 b = *reinterpret_cast<const float4*>(in + base + 4);
    uint4 o;
    o.x = (unsigned)f2bf(a.x) | ((unsigned)f2bf(a.y) << 16);
    o.y = (unsigned)f2bf(a.z) | ((unsigned)f2bf(a.w) << 16);
    o.z = (unsigned)f2bf(b.x) | ((unsigned)f2bf(b.y) << 16);
    o.w = (unsigned)f2bf(b.z) | ((unsigned)f2bf(b.w) << 16);
    *reinterpret_cast<uint4*>(out + base) = o;
}

// ---------------------------------------------------------------- RoPE tables
__global__ __launch_bounds__(256) void build_rope(float* __restrict__ cosT,
                                                  float* __restrict__ sinT) {
    int i = blockIdx.x * 256 + threadIdx.x;
    if (i >= TT * 32) return;
    int t = i >> 5, j = i & 31;
    float freq = exp2f(-5.0f * (float)j * (1.0f / 32.0f));  // 32^(-j/32)
    float ang  = (float)t * freq;
    cosT[i] = cosf(ang);
    sinT[i] = sinf(ang);
}

// ---------------------------------------------------------------- GEMM: C[M][N] = A[M][K] * Bt[N][K]^T
// bf16 in, fp32 out. 128x128 tile, BK=64, 4 waves (2x2).
// Staging: global_load_lds width=16, linear LDS dest + pre-swizzled global source;
// reads use the same XOR-granule involution -> conflict-free ds_read_b128.
__global__ __launch_bounds__(256) void gemm_bt(const unsigned short* __restrict__ A,
                                               const unsigned short* __restrict__ Bt,
                                               float* __restrict__ C,
                                               int M, int N, int K) {
    __shared__ alignas(16) unsigned short sA[128 * 64];
    __shared__ alignas(16) unsigned short sB[128 * 64];
    const int t    = threadIdx.x;
    const int nb   = N >> 7;
    const int m0   = (blockIdx.x / nb) << 7;
    const int n0   = (blockIdx.x % nb) << 7;
    const int w    = t >> 6, lane = t & 63;
    const int wr   = w >> 1, wc = w & 1;
    const int lrow = lane & 15, lk = lane >> 4;
    const int r_   = t >> 3;            // staging row-within-32-group
    const int c_   = t & 7;             // linear 16B granule (LDS dest)
    const int pg   = c_ ^ (r_ & 7);     // swizzled granule (global source)

    f32x4 acc[4][4] = {};

    for (int kt = 0; kt < K; kt += 64) {
        __syncthreads();
#pragma unroll
        for (int i = 0; i < 4; i++) {
            gload_lds16(A  + (size_t)(m0 + i * 32 + r_) * K + kt + pg * 8, sA + i * 2048 + w * 512);
            gload_lds16(Bt + (size_t)(n0 + i * 32 + r_) * K + kt + pg * 8, sB + i * 2048 + w * 512);
        }
        __syncthreads();
#pragma unroll
        for (int ks = 0; ks < 2; ks++) {
            bf16x8 af[4], bfr[4];
#pragma unroll
            for (int mi = 0; mi < 4; mi++) {
                int rowa = wr * 64 + mi * 16 + lrow;
                int ga   = (ks * 4 + lk) ^ (rowa & 7);
                af[mi]   = *reinterpret_cast<const bf16x8*>(&sA[rowa * 64 + ga * 8]);
                int rowb = wc * 64 + mi * 16 + lrow;
                int gb   = (ks * 4 + lk) ^ (rowb & 7);
                bfr[mi]  = *reinterpret_cast<const bf16x8*>(&sB[rowb * 64 + gb * 8]);
            }
#pragma unroll
            for (int mi = 0; mi < 4; mi++)
#pragma unroll
                for (int ni = 0; ni < 4; ni++)
                    acc[mi][ni] = __builtin_amdgcn_mfma_f32_16x16x32_bf16(af[mi], bfr[ni], acc[mi][ni], 0, 0, 0);
        }
    }
    // epilogue: C/D layout col=lane&15, row=(lane>>4)*4+i
#pragma unroll
    for (int mi = 0; mi < 4; mi++)
#pragma unroll
        for (int ni = 0; ni < 4; ni++) {
            int row = m0 + wr * 64 + mi * 16 + lk * 4;
            int col = n0 + wc * 64 + ni * 16 + lrow;
#pragma unroll
            for (int i = 0; i < 4; i++)
                C[(size_t)(row + i) * N + col] = acc[mi][ni][i];
        }
}

// ---------------------------------------------------------------- RMSNorm + RoPE epilogue
// One wave per (sel,b,t,h) row of 64. sel: 0=q,1=k,2=v(copy).
// Q gets *0.125*log2(e) folded in (exp2-based softmax downstream).
__global__ __launch_bounds__(256) void norm_rope(const float* __restrict__ qkv,
                                                 const float* __restrict__ cosT,
                                                 const float* __restrict__ sinT,
                                                 const float* __restrict__ qw,
                                                 const float* __restrict__ kw,
                                                 unsigned short* __restrict__ Qo,
                                                 unsigned short* __restrict__ Ko,
                                                 unsigned short* __restrict__ Vo) {
    int wv = threadIdx.x >> 6, lane = threadIdx.x & 63;
    int rid = blockIdx.x * 4 + wv;           // 0 .. 3*65536-1
    int sel = rid >> 16;
    int rem = rid & 65535;
    int h   = rem & 15;
    int bt  = rem >> 4;                      // b*T + t
    int tp  = bt & (TT - 1);
    int b   = bt >> 11;
    float v = qkv[(size_t)bt * 3072 + sel * 1024 + h * 64 + lane];
    unsigned short* dst = (sel == 0) ? Qo : ((sel == 1) ? Ko : Vo);
    size_t didx = ((size_t)(b * NH + h) * TT + tp) * 64 + lane;
    float outv;
    if (sel < 2) {
        float ss = v * v;
#pragma unroll
        for (int m = 32; m; m >>= 1) ss += __shfl_xor(ss, m);
        float r = rsqrtf(ss * (1.0f / 64.0f) + 1e-6f);
        const float* wgt = sel ? kw : qw;
        float nv = v * r * wgt[lane];
        float other = __shfl_xor(nv, 32);
        int j = lane & 31;
        float c = cosT[tp * 32 + j], s = sinT[tp * 32 + j];
        outv = (lane < 32) ? (nv * c - other * s) : (nv * c + other * s);
        if (sel == 0) outv *= 0.125f * 1.4426950408889634f;  // scale * log2(e): exp2 softmax
    } else {
        outv = v;
    }
    dst[didx] = f2bf(outv);
}

// ---------------------------------------------------------------- V transpose: [bh][t][d] -> [bh][d][t]
__global__ __launch_bounds__(256) void transpose_v(const unsigned short* __restrict__ Vb,
                                                   unsigned short* __restrict__ Vt) {
    __shared__ unsigned short s[64 * 68];
    const int t0 = blockIdx.x * 64, bh = blockIdx.y;
    const unsigned short* src = Vb + (size_t)bh * TT * 64;
    const int r = threadIdx.x >> 2, g4 = threadIdx.x & 3;
#pragma unroll
    for (int p = 0; p < 2; p++) {
        int g = g4 + p * 4;
        *reinterpret_cast<uint4*>(&s[r * 68 + g * 8]) =
            *reinterpret_cast<const uint4*>(src + (size_t)(t0 + r) * 64 + g * 8);
    }
    __syncthreads();
#pragma unroll
    for (int p = 0; p < 2; p++) {
        int tt = (g4 + p * 4) * 8;
        unsigned short tmp[8];
#pragma unroll
        for (int j = 0; j < 8; j++) tmp[j] = s[(tt + j) * 68 + r];   // column r = d
        *reinterpret_cast<uint4*>(Vt + ((size_t)bh * 64 + r) * TT + t0 + tt) =
            *reinterpret_cast<uint4*>(tmp);
    }
}

// ---------------------------------------------------------------- causal flash attention
// Block: (x, bh) with qt = (x + bh) & 31. 4 waves, QBLK=64, KVBLK=64.
// K/V^T staged via global_load_lds (async DMA, zero register liveness across barriers;
// linear LDS dest + XOR-granule pre-swizzled source, same involution on reads).
// exp2-based online softmax with defer-max (THR=8) and deferred l-reduce.
__global__ __launch_bounds__(256) void attn_fwd(const unsigned short* __restrict__ Qm,
                                                const unsigned short* __restrict__ Km,
                                                const unsigned short* __restrict__ Vt,
                                                unsigned short* __restrict__ Om) {
    __shared__ alignas(16) unsigned short sQ[64 * 68];
    __shared__ alignas(16) unsigned short sK[64 * 64];    // linear+swizzled (gload_lds dest)
    __shared__ alignas(16) unsigned short sVT[64 * 64];   // [d][kv], linear+swizzled
    __shared__ alignas(16) unsigned short sP[4][16 * 68]; // per-wave P tile
    const int bh = blockIdx.y;
    const int qt = (blockIdx.x + blockIdx.y) & 31;   // balance triangular work across CUs
    const int b = bh >> 4, h = bh & 15;
    const unsigned short* Qp = Qm + (size_t)bh * TT * 64;
    const unsigned short* Kp = Km + (size_t)bh * TT * 64;
    const unsigned short* Vp = Vt + (size_t)bh * 64 * TT;   // [d][t]
    const int t = threadIdx.x, wv = t >> 6, lane = t & 63;
    const int lrow = lane & 15, lk = lane >> 4;
    const int r_ = t >> 3;            // staging row-within-32-group
    const int c_ = t & 7;             // linear granule (LDS dest)
    const int pg = c_ ^ (r_ & 7);     // swizzled granule (global source)

    // stage Q tile once (padded 68: plain stores, read 2-way-free)
#pragma unroll
    for (int i = 0; i < 2; i++) {
        int r = i * 32 + r_;
        *reinterpret_cast<uint4*>(&sQ[r * 68 + c_ * 8]) =
            *reinterpret_cast<const uint4*>(Qp + (size_t)(qt * 64 + r) * 64 + c_ * 8);
    }
    __syncthreads();
    bf16x8 aq0 = *reinterpret_cast<const bf16x8*>(&sQ[(wv * 16 + lrow) * 68 + lk * 8]);
    bf16x8 aq1 = *reinterpret_cast<const bf16x8*>(&sQ[(wv * 16 + lrow) * 68 + 32 + lk * 8]);

    f32x4 o[4] = {};
    float mrun[4], lsum[4];
#pragma unroll
    for (int i = 0; i < 4; i++) { mrun[i] = -__builtin_inff(); lsum[i] = 0.0f; }

    for (int kt = 0; kt <= qt; kt++) {
        __syncthreads();   // prior tile's reads of sK/sVT complete
#pragma unroll
        for (int i = 0; i < 2; i++) {
            // K rows i*32+r_, 64-wide: linear dest t*16B, swizzled source granule
            gload_lds16(Kp + (size_t)(kt * 64 + i * 32 + r_) * 64 + pg * 8, sK + i * 2048 + wv * 512);
            // V^T rows d=i*32+r_, kv-window [kt*64, kt*64+64)
            gload_lds16(Vp + (size_t)(i * 32 + r_) * TT + kt * 64 + pg * 8, sVT + i * 2048 + wv * 512);
        }
        __syncthreads();   // vmcnt(0) drained by compiler before barrier

        // S = Q K^T  (scale*log2e pre-folded into Q); granule g^(row&7) undoes swizzle
        f32x4 s[4];
#pragma unroll
        for (int nt = 0; nt < 4; nt++) {
            int row = nt * 16 + lrow;
            f32x4 z = {0.f, 0.f, 0.f, 0.f};
            z = __builtin_amdgcn_mfma_f32_16x16x32_bf16(
                aq0, *reinterpret_cast<const bf16x8*>(&sK[row * 64 + (lk ^ (row & 7)) * 8]), z, 0, 0, 0);
            z = __builtin_amdgcn_mfma_f32_16x16x32_bf16(
                aq1, *reinterpret_cast<const bf16x8*>(&sK[row * 64 + ((4 + lk) ^ (row & 7)) * 8]), z, 0, 0, 0);
            s[nt] = z;
        }
        if (kt == qt) {   // diagonal tile: causal mask (kv_local > q_local)
#pragma unroll
            for (int nt = 0; nt < 4; nt++)
#pragma unroll
                for (int i = 0; i < 4; i++)
                    if (nt * 16 + lrow > wv * 16 + lk * 4 + i) s[nt][i] = -__builtin_inff();
        }

        // defer-max online softmax (log2 domain)
        float pm[4];
#pragma unroll
        for (int i = 0; i < 4; i++)
            pm[i] = fmaxf(fmaxf(s[0][i], s[1][i]), fmaxf(s[2][i], s[3][i]));
        bool skip = __all(pm[0] <= mrun[0] + 8.0f && pm[1] <= mrun[1] + 8.0f &&
                          pm[2] <= mrun[2] + 8.0f && pm[3] <= mrun[3] + 8.0f);
        if (!skip) {
#pragma unroll
            for (int i = 0; i < 4; i++) {
                float a = pm[i];
#pragma unroll
                for (int msk = 8; msk; msk >>= 1) a = fmaxf(a, __shfl_xor(a, msk));
                float mn = fmaxf(mrun[i], a);
                float fsc = exp2f(mrun[i] - mn);
                mrun[i] = mn;
                lsum[i] *= fsc;
#pragma unroll
                for (int dt = 0; dt < 4; dt++) o[dt][i] *= fsc;
            }
        }
#pragma unroll
        for (int nt = 0; nt < 4; nt++)
#pragma unroll
            for (int i = 0; i < 4; i++)
                s[nt][i] = exp2f(s[nt][i] - mrun[i]);
#pragma unroll
        for (int i = 0; i < 4; i++)
            lsum[i] += (s[0][i] + s[1][i]) + (s[2][i] + s[3][i]);   // per-lane partial; reduced at end

        // P -> LDS (wave-private, pad 68) -> A-frags
        unsigned short* myP = &sP[wv][0];
#pragma unroll
        for (int nt = 0; nt < 4; nt++)
#pragma unroll
            for (int i = 0; i < 4; i++)
                myP[(lk * 4 + i) * 68 + nt * 16 + lrow] = f2bf(s[nt][i]);
        bf16x8 pa0 = *reinterpret_cast<const bf16x8*>(&myP[lrow * 68 + lk * 8]);
        bf16x8 pa1 = *reinterpret_cast<const bf16x8*>(&myP[lrow * 68 + 32 + lk * 8]);
#pragma unroll
        for (int dt = 0; dt < 4; dt++) {
            int row = dt * 16 + lrow;
            o[dt] = __builtin_amdgcn_mfma_f32_16x16x32_bf16(
                pa0, *reinterpret_cast<const bf16x8*>(&sVT[row * 64 + (lk ^ (row & 7)) * 8]), o[dt], 0, 0, 0);
            o[dt] = __builtin_amdgcn_mfma_f32_16x16x32_bf16(
                pa1, *reinterpret_cast<const bf16x8*>(&sVT[row * 64 + ((4 + lk) ^ (row & 7)) * 8]), o[dt], 0, 0, 0);
        }
    }

    // final cross-lane l reduce (deferred), then normalize + store to [B*T][1024]
    float inv[4];
#pragma unroll
    for (int i = 0; i < 4; i++) {
        float a = lsum[i];
#pragma unroll
        for (int msk = 8; msk; msk >>= 1) a += __shfl_xor(a, msk);
        inv[i] = 1.0f / a;
    }
    int qrow = qt * 64 + wv * 16 + lk * 4;
#pragma unroll
    for (int dt = 0; dt < 4; dt++)
#pragma unroll
        for (int i = 0; i < 4; i++) {
            size_t idx = ((size_t)(b * TT + qrow + i)) * 1024 + h * 64 + dt * 16 + lrow;
            Om[idx] = f2bf(o[dt][i] * inv[i]);
        }
}

// ---------------------------------------------------------------- launch
extern "C" void kernel_launch(void* const* d_in, const int* in_sizes, int n_in,
                              void* d_out, int out_size, void* d_ws, size_t ws_size,
                              hipStream_t stream) {
    const float* x      = (const float*)d_in[0];
    const float* w_qkv  = (const float*)d_in[1];
    const float* w_proj = (const float*)d_in[2];
    const float* qw     = (const float*)d_in[3];
    const float* kw     = (const float*)d_in[4];
    float* out = (float*)d_out;
    char* ws = (char*)d_ws;

    // workspace layout (bytes); total ~92.8 MB (Vt aliases dead qkvf region)
    unsigned short* xb     = (unsigned short*)(ws + 0);            // 8,388,608  (aliased by attnb later)
    unsigned short* wqkvb  = (unsigned short*)(ws + 8388608);      // 6,291,456
    unsigned short* wprojb = (unsigned short*)(ws + 14680064);     // 2,097,152
    float*          qkvf   = (float*)(ws + 16777216);              // 50,331,648 (dead after norm_rope)
    unsigned short* Vtb    = (unsigned short*)(ws + 16777216);     // 8,388,608  (alias into qkvf)
    unsigned short* Qb     = (unsigned short*)(ws + 67108864);     // 8,388,608
    unsigned short* Kb     = (unsigned short*)(ws + 75497472);     // 8,388,608
    unsigned short* Vb     = (unsigned short*)(ws + 83886080);     // 8,388,608
    float*          cosT   = (float*)(ws + 92274688);              // 262,144
    float*          sinT   = (float*)(ws + 92536832);              // 262,144
    unsigned short* attnb  = xb;  // alias: x consumed by GEMM1 before attn writes

    cvt_bf16<<<2048, 256, 0, stream>>>(x, xb, BT * DIM);
    cvt_bf16<<<1536, 256, 0, stream>>>(w_qkv, wqkvb, 3 * DIM * DIM);
    cvt_bf16<<<512, 256, 0, stream>>>(w_proj, wprojb, DIM * DIM);
    build_rope<<<256, 256, 0, stream>>>(cosT, sinT);
    gemm_bt<<<(BT / 128) * (3 * DIM / 128), 256, 0, stream>>>(xb, wqkvb, qkvf, BT, 3 * DIM, DIM);
    norm_rope<<<3 * BT * NH / 4, 256, 0, stream>>>(qkvf, cosT, sinT, qw, kw, Qb, Kb, Vb);
    transpose_v<<<dim3(TT / 64, BHN), 256, 0, stream>>>(Vb, Vtb);
    attn_fwd<<<dim3(TT / 64, BHN), 256, 0, stream>>>(Qb, Kb, Vtb, attnb);
    gemm_bt<<<(BT / 128) * (DIM / 128), 256, 0, stream>>>(attnb, wprojb, out, BT, DIM, DIM);
    (void)in_sizes; (void)n_in; (void)out_size; (void)ws_size;
}